// Round 1
// baseline (366.978 us; speedup 1.0000x reference)
//
#include <hip/hip_runtime.h>

// NF4 dequant + GEMV:  out[b,o] = sum_i x[b,i] * NF4[codes[o,i]] * absmax[o,i/64]
// Shapes: x[8,1,4096] f32, codes[16384,4096] i32 (values 0..15), absmax[16384,64] f32
// out[8,1,16384] f32.
// HBM-bound: codes = 256 MiB dominates -> floor ~43 us at 6.3 TB/s.

#define IN_F   4096
#define OUT_F  16384
#define NBLK   64          // absmax blocks per row = IN_F/64
#define ROWS   8           // output rows per wave
#define BATCH  8
#define K_VEC  (IN_F / 4)  // int4 / float4 elements per row = 1024
#define K_ITER (K_VEC / 64)  // 16 K-steps per lane

__device__ __constant__ float NF4_CODE_C[16] = {
    -1.0f, -0.6961928009986877f, -0.5250730514526367f, -0.39491748809814453f,
    -0.28444138169288635f, -0.18477343022823334f, -0.09105003625154495f, 0.0f,
    0.07958029955625534f, 0.16093020141124725f, 0.24611230194568634f,
    0.33791524171829224f, 0.44070982933044434f, 0.5626170039176941f,
    0.7229568362236023f, 1.0f};

__global__ __launch_bounds__(256, 2) void nf4_gemv(
    const float* __restrict__ x,       // [8, 4096]
    const int* __restrict__ codes,     // [16384, 4096]
    const float* __restrict__ absmax,  // [16384, 64]
    float* __restrict__ out)           // [8, 16384]
{
    __shared__ float lut[16];
    if (threadIdx.x < 16) lut[threadIdx.x] = NF4_CODE_C[threadIdx.x];
    __syncthreads();

    const int lane   = threadIdx.x & 63;
    const int wave   = threadIdx.x >> 6;
    const int gwave  = blockIdx.x * 4 + wave;
    const int o_base = gwave * ROWS;

    const int4*   codes4 = (const int4*)codes;
    const float4* x4     = (const float4*)x;

    // Preload this wave's absmax rows: lane i holds absmax[o, i] (NBLK==64==wave size)
    float a_reg[ROWS];
#pragma unroll
    for (int r = 0; r < ROWS; ++r)
        a_reg[r] = absmax[(size_t)(o_base + r) * NBLK + lane];

    float acc[ROWS][BATCH];
#pragma unroll
    for (int r = 0; r < ROWS; ++r)
#pragma unroll
        for (int b = 0; b < BATCH; ++b) acc[r][b] = 0.0f;

    for (int t = 0; t < K_ITER; ++t) {
        const int vec = t * 64 + lane;  // float4/int4 index within a row

        int4 cr[ROWS];
#pragma unroll
        for (int r = 0; r < ROWS; ++r)
            cr[r] = codes4[(size_t)(o_base + r) * K_VEC + vec];

        float4 xv[BATCH];
#pragma unroll
        for (int b = 0; b < BATCH; ++b)
            xv[b] = x4[b * K_VEC + vec];

#pragma unroll
        for (int r = 0; r < ROWS; ++r) {
            // absmax block index for this lane's 4 elements: i0/64 = t*4 + lane/16
            const float am = __shfl(a_reg[r], t * 4 + (lane >> 4), 64);
            const float w0 = lut[cr[r].x & 15] * am;
            const float w1 = lut[cr[r].y & 15] * am;
            const float w2 = lut[cr[r].z & 15] * am;
            const float w3 = lut[cr[r].w & 15] * am;
#pragma unroll
            for (int b = 0; b < BATCH; ++b) {
                float s = acc[r][b];
                s = fmaf(w0, xv[b].x, s);
                s = fmaf(w1, xv[b].y, s);
                s = fmaf(w2, xv[b].z, s);
                s = fmaf(w3, xv[b].w, s);
                acc[r][b] = s;
            }
        }
    }

    // Cross-lane reduction: each acc[r][b] summed over the 64 lanes
#pragma unroll
    for (int r = 0; r < ROWS; ++r)
#pragma unroll
        for (int b = 0; b < BATCH; ++b) {
            float v = acc[r][b];
#pragma unroll
            for (int off = 32; off > 0; off >>= 1)
                v += __shfl_xor(v, off, 64);
            acc[r][b] = v;
        }

    if (lane == 0) {
#pragma unroll
        for (int r = 0; r < ROWS; ++r)
#pragma unroll
            for (int b = 0; b < BATCH; ++b)
                out[b * OUT_F + o_base + r] = acc[r][b];
    }
}

extern "C" void kernel_launch(void* const* d_in, const int* in_sizes, int n_in,
                              void* d_out, int out_size, void* d_ws, size_t ws_size,
                              hipStream_t stream) {
    const float* x      = (const float*)d_in[0];
    const int*   codes  = (const int*)d_in[1];
    const float* absmax = (const float*)d_in[2];
    float*       out    = (float*)d_out;

    // 16384 rows / (8 rows/wave * 4 waves/block) = 512 blocks
    dim3 grid(OUT_F / (ROWS * 4));
    dim3 block(256);
    nf4_gemv<<<grid, block, 0, stream>>>(x, codes, absmax, out);
}